// Round 1
// baseline (151.470 us; speedup 1.0000x reference)
//
#include <hip/hip_runtime.h>
#include <hip/hip_bf16.h>

// Problem constants (fixed by reference): N=4096, D=256, T=0.5, EPS=1e-8
#define PN   4096
#define PN2  8192
#define PD   256
#define TILE 128
#define NBLK (PN2 / TILE)              // 64 tile-blocks per dim
#define NTRI (NBLK * (NBLK + 1) / 2)   // 2080 upper-tri blocks

typedef __attribute__((ext_vector_type(8))) short bf16x8;   // 8 bf16 = 4 VGPRs
typedef __attribute__((ext_vector_type(4))) float f32x4;

// ---------------------------------------------------------------------------
// Kernel 1: row-normalize z = [z_i; z_j] (fp32), write bf16 zn, zero rowsum.
// Wave-per-row: float4 loads, shuffle-reduce within the wave, 8B packed store.
// No LDS, no __syncthreads.
// ---------------------------------------------------------------------------
__global__ __launch_bounds__(256) void normalize_kernel(
    const float* __restrict__ zi, const float* __restrict__ zj,
    __hip_bfloat16* __restrict__ zn, float* __restrict__ rowsum) {
  const int wave = threadIdx.x >> 6;
  const int lane = threadIdx.x & 63;
  const int r = blockIdx.x * 4 + wave;           // 0..8191
  const float* src = (r < PN) ? (zi + (size_t)r * PD) : (zj + (size_t)(r - PN) * PD);
  float4 x = *(const float4*)(src + lane * 4);   // 16B/lane, coalesced
  float s = x.x * x.x + x.y * x.y + x.z * x.z + x.w * x.w;
  #pragma unroll
  for (int off = 32; off >= 1; off >>= 1) s += __shfl_xor(s, off, 64);
  float inv = 1.0f / fmaxf(sqrtf(s), 1e-8f);
  union { ushort4 u; __hip_bfloat16 h[4]; } o;
  o.h[0] = __float2bfloat16(x.x * inv);
  o.h[1] = __float2bfloat16(x.y * inv);
  o.h[2] = __float2bfloat16(x.z * inv);
  o.h[3] = __float2bfloat16(x.w * inv);
  *(ushort4*)((unsigned short*)zn + (size_t)r * PD + lane * 4) = o.u;  // 8B/lane
  if (lane == 0) rowsum[r] = 0.0f;   // ws is re-poisoned 0xAA before every launch
}

// ---------------------------------------------------------------------------
// Kernel 2: sim = zn @ zn^T, UPPER-TRIANGULAR blocks only (symmetry).
// zn is 4 MiB -> fully resident in every XCD's 4 MiB L2 (FETCH_SIZE confirmed
// ~8x4MiB compulsory). So: NO LDS staging, NO barriers. Each wave gathers its
// MFMA fragments straight from global (L2-hit), 2-deep register double-buffer,
// 8 fully-unrolled k-steps (K=256 / 32). Fragment mapping identical to the
// LDS version: lane holds zn[frag_row + (lane&15)][ks*32 + (lane>>4)*8 + j].
// ---------------------------------------------------------------------------
__global__ __launch_bounds__(256) void simsum_kernel(
    const __hip_bfloat16* __restrict__ zn,
    float* __restrict__ rowsum, float* __restrict__ pos) {
  // Decode upper-tri (bi<=bj) from linear index: bj columns, T(bj)=bj(bj+1)/2
  const int idx = blockIdx.x;
  int bj = (int)((sqrtf(8.0f * (float)idx + 1.0f) - 1.0f) * 0.5f);
  while ((bj + 1) * (bj + 2) / 2 <= idx) ++bj;
  while (bj * (bj + 1) / 2 > idx) --bj;
  const int bi = idx - bj * (bj + 1) / 2;
  const bool diagBlk = (bi == bj);
  const bool posBlk  = (bj == bi + PN / TILE);   // cols == rows + 4096

  const int tid  = threadIdx.x;
  const int wave = tid >> 6;
  const int lane = tid & 63;
  const int quad = lane >> 4;
  const int c16  = lane & 15;
  const int rowBase = bi * TILE;
  const int colBase = bj * TILE;
  const int waveRow = (wave >> 1) * 64;
  const int waveCol = (wave & 1) * 64;

  // Per-lane fragment base pointers. A row = m-index, B "row" of zn = sim col.
  const unsigned short* zs = (const unsigned short*)zn;
  const unsigned short* baseA = zs + (size_t)(rowBase + waveRow + c16) * PD + quad * 8;
  const unsigned short* baseB = zs + (size_t)(colBase + waveCol + c16) * PD + quad * 8;

  f32x4 acc[4][4];
  #pragma unroll
  for (int i = 0; i < 4; ++i)
    #pragma unroll
    for (int j = 0; j < 4; ++j)
      acc[i][j] = (f32x4){0.f, 0.f, 0.f, 0.f};

  // 2-deep register double-buffer; all indices static after full unroll.
  bf16x8 abuf[2][4], bbuf[2][4];
  #pragma unroll
  for (int mi = 0; mi < 4; ++mi) {
    abuf[0][mi] = *(const bf16x8*)(baseA + mi * 16 * PD);
    bbuf[0][mi] = *(const bf16x8*)(baseB + mi * 16 * PD);
  }
  #pragma unroll
  for (int ks = 0; ks < PD / 32; ++ks) {         // 8 k-steps
    const int cur = ks & 1;
    const int nxt = cur ^ 1;
    if (ks < PD / 32 - 1) {
      #pragma unroll
      for (int mi = 0; mi < 4; ++mi) {
        abuf[nxt][mi] = *(const bf16x8*)(baseA + mi * 16 * PD + (ks + 1) * 32);
        bbuf[nxt][mi] = *(const bf16x8*)(baseB + mi * 16 * PD + (ks + 1) * 32);
      }
    }
    #pragma unroll
    for (int mi = 0; mi < 4; ++mi)
      #pragma unroll
      for (int ni = 0; ni < 4; ++ni)
        acc[mi][ni] = __builtin_amdgcn_mfma_f32_16x16x32_bf16(
            abuf[cur][mi], bbuf[cur][ni], acc[mi][ni], 0, 0, 0);
  }

  // Epilogue (unchanged, verified). C/D layout: col=lane&15, row=quad*4+reg.
  float colsum[4] = {0.f, 0.f, 0.f, 0.f};   // per-ni column partials (off-diag)
  #pragma unroll
  for (int mi = 0; mi < 4; ++mi) {
    int rbase = rowBase + waveRow + mi * 16 + quad * 4;
    float rs[4] = {0.f, 0.f, 0.f, 0.f};
    #pragma unroll
    for (int ni = 0; ni < 4; ++ni) {
      int gcol = colBase + waveCol + ni * 16 + c16;
      #pragma unroll
      for (int t = 0; t < 4; ++t) {
        int grow = rbase + t;
        float sim = acc[mi][ni][t];
        float e = __expf(2.0f * sim);               // exp(sim / T), T=0.5
        if (diagBlk && gcol == grow) e = 0.0f;      // mask diagonal
        rs[t] += e;
        colsum[ni] += e;
        if (posBlk && gcol == grow + PN) {          // positive pair (and mirror)
          pos[grow] = sim;
          pos[grow + PN] = sim;
        }
      }
    }
    #pragma unroll
    for (int t = 0; t < 4; ++t) {
      #pragma unroll
      for (int off = 1; off <= 8; off <<= 1) rs[t] += __shfl_xor(rs[t], off, 64);
    }
    if (c16 == 0) {
      #pragma unroll
      for (int t = 0; t < 4; ++t) atomicAdd(&rowsum[rbase + t], rs[t]);
    }
  }
  if (!diagBlk) {   // column contributions = mirrored rows (symmetry)
    #pragma unroll
    for (int ni = 0; ni < 4; ++ni) {
      float cs = colsum[ni];
      cs += __shfl_xor(cs, 16, 64);
      cs += __shfl_xor(cs, 32, 64);
      if (quad == 0) atomicAdd(&rowsum[colBase + waveCol + ni * 16 + c16], cs);
    }
  }
}

// ---------------------------------------------------------------------------
// Kernel 3: loss_i = log(denom_i) - 2*pos_i ; out = sum(w*loss)/sum(w)
// ---------------------------------------------------------------------------
__global__ __launch_bounds__(1024) void finalize_kernel(
    const float* __restrict__ rowsum, const float* __restrict__ pos,
    const float* __restrict__ w, float* __restrict__ out) {
  int tid = threadIdx.x;
  float wl = 0.f, ws = 0.f;
  for (int i = tid; i < PN2; i += 1024) {
    float li = logf(rowsum[i]) - 2.0f * pos[i];
    float wi = w[i & (PN - 1)];
    wl += wi * li;
    ws += wi;
  }
  #pragma unroll
  for (int off = 32; off >= 1; off >>= 1) {
    wl += __shfl_xor(wl, off, 64);
    ws += __shfl_xor(ws, off, 64);
  }
  __shared__ float pl[16], pw[16];
  if ((tid & 63) == 0) { pl[tid >> 6] = wl; pw[tid >> 6] = ws; }
  __syncthreads();
  if (tid == 0) {
    float sl = 0.f, sw = 0.f;
    #pragma unroll
    for (int k = 0; k < 16; ++k) { sl += pl[k]; sw += pw[k]; }
    out[0] = sl / sw;
  }
}

// ---------------------------------------------------------------------------
extern "C" void kernel_launch(void* const* d_in, const int* in_sizes, int n_in,
                              void* d_out, int out_size, void* d_ws, size_t ws_size,
                              hipStream_t stream) {
  const float* zi = (const float*)d_in[0];
  const float* zj = (const float*)d_in[1];
  const float* w  = (const float*)d_in[2];
  float* out = (float*)d_out;

  // Workspace: zn bf16 [8192*256] = 4 MiB, then rowsum f32[8192], pos f32[8192]
  __hip_bfloat16* zn = (__hip_bfloat16*)d_ws;
  float* rowsum = (float*)((char*)d_ws + (size_t)PN2 * PD * 2);
  float* pos = rowsum + PN2;

  normalize_kernel<<<PN2 / 4, 256, 0, stream>>>(zi, zj, zn, rowsum);
  simsum_kernel<<<NTRI, 256, 0, stream>>>(zn, rowsum, pos);
  finalize_kernel<<<1, 1024, 0, stream>>>(rowsum, pos, w, out);
}

// Round 2
// 135.303 us; speedup vs baseline: 1.1195x; 1.1195x over previous
//
#include <hip/hip_runtime.h>
#include <hip/hip_bf16.h>

// Problem constants (fixed by reference): N=4096, D=256, T=0.5, EPS=1e-8
#define PN   4096
#define PN2  8192
#define PD   256
#define TILE 128
#define BK   64
#define NBLK (PN2 / TILE)              // 64 tile-blocks per dim
#define NTRI (NBLK * (NBLK + 1) / 2)   // 2080 upper-tri blocks

typedef __attribute__((ext_vector_type(8))) short bf16x8;   // 8 bf16 = 4 VGPRs
typedef __attribute__((ext_vector_type(4))) float f32x4;

typedef const __attribute__((address_space(1))) void* gas_ptr;
typedef __attribute__((address_space(3))) void* las_ptr;

// ---------------------------------------------------------------------------
// Kernel 1: row-normalize z = [z_i; z_j] (fp32), write bf16 zn; zero rowsum,
// pos, ticket. Wave-per-row: float4 loads, shuffle-reduce, 8B packed store.
// ---------------------------------------------------------------------------
__global__ __launch_bounds__(256) void normalize_kernel(
    const float* __restrict__ zi, const float* __restrict__ zj,
    __hip_bfloat16* __restrict__ zn, float* __restrict__ rowsum,
    float* __restrict__ pos, unsigned* __restrict__ ticket) {
  const int wave = threadIdx.x >> 6;
  const int lane = threadIdx.x & 63;
  const int r = blockIdx.x * 4 + wave;           // 0..8191
  const float* src = (r < PN) ? (zi + (size_t)r * PD) : (zj + (size_t)(r - PN) * PD);
  float4 x = *(const float4*)(src + lane * 4);   // 16B/lane, coalesced
  float s = x.x * x.x + x.y * x.y + x.z * x.z + x.w * x.w;
  #pragma unroll
  for (int off = 32; off >= 1; off >>= 1) s += __shfl_xor(s, off, 64);
  float inv = 1.0f / fmaxf(sqrtf(s), 1e-8f);
  union { ushort4 u; __hip_bfloat16 h[4]; } o;
  o.h[0] = __float2bfloat16(x.x * inv);
  o.h[1] = __float2bfloat16(x.y * inv);
  o.h[2] = __float2bfloat16(x.z * inv);
  o.h[3] = __float2bfloat16(x.w * inv);
  *(ushort4*)((unsigned short*)zn + (size_t)r * PD + lane * 4) = o.u;  // 8B/lane
  if (lane == 0) rowsum[r] = 0.0f;   // ws is re-poisoned 0xAA before every launch
  if (lane == 1) pos[r] = 0.0f;      // pos now accumulated via atomicAdd
  if (r == 0 && lane == 2) *ticket = 0u;
}

// ---------------------------------------------------------------------------
// Kernel 2: sim = zn @ zn^T, UPPER-TRIANGULAR blocks only (symmetry).
// Round-0 LDS structure (proven 43.8us) + double-buffered staging with ONE
// barrier per kt-step (T3 minimum 2-phase): stage kt+1 into buf^1, compute kt
// from buf, then a single __syncthreads (vmcnt(0)+lgkmcnt(0) drain) per step.
// Finalize is fused: atomic ticket; the last block reduces rowsum/pos -> out.
// ---------------------------------------------------------------------------
__global__ __launch_bounds__(256) void simsum_kernel(
    const __hip_bfloat16* __restrict__ zn,
    float* __restrict__ rowsum, float* __restrict__ pos,
    const float* __restrict__ w, float* __restrict__ out,
    unsigned* __restrict__ ticket) {
  __shared__ char lds[2 * 2 * TILE * BK * 2];   // 64 KiB: [buf][As|Bs]

  // Decode upper-tri (bi<=bj) from linear index: bj columns, T(bj)=bj(bj+1)/2
  const int idx = blockIdx.x;
  int bj = (int)((sqrtf(8.0f * (float)idx + 1.0f) - 1.0f) * 0.5f);
  while ((bj + 1) * (bj + 2) / 2 <= idx) ++bj;
  while (bj * (bj + 1) / 2 > idx) --bj;
  const int bi = idx - bj * (bj + 1) / 2;
  const bool diagBlk = (bi == bj);
  const bool posBlk  = (bj == bi + PN / TILE);   // cols == rows + 4096

  const int tid  = threadIdx.x;
  const int wave = tid >> 6;
  const int lane = tid & 63;
  const int quad = lane >> 4;
  const int c16  = lane & 15;
  const int rowBase = bi * TILE;
  const int colBase = bj * TILE;
  const int waveRow = (wave >> 1) * 64;
  const int waveCol = (wave & 1) * 64;
  const int subrow = lane >> 3;  // 0..7 (row within an 8-row issue)
  const int slot   = lane & 7;   // 0..7 (16B chunk slot within a 128B LDS row)

  f32x4 acc[4][4];
  #pragma unroll
  for (int i = 0; i < 4; ++i)
    #pragma unroll
    for (int j = 0; j < 4; ++j)
      acc[i][j] = (f32x4){0.f, 0.f, 0.f, 0.f};

  // Stage one BK=64 K-slab of A (and B if off-diag) into LDS, pre-swizzled
  // global source so LDS rows land in XOR-swizzled chunk order (linear dest,
  // rule #21). 16 issues of 1KiB each (8 rows x 128B).
#define STAGE(DSTA, DSTB, KT) do {                                            \
    _Pragma("unroll")                                                         \
    for (int p = 0; p < 4; ++p) {                                             \
      int issue = wave * 4 + p;                                               \
      int rr = issue * 8 + subrow;                                            \
      int cc = slot ^ (rr & 7);                                               \
      const __hip_bfloat16* ga = zn + (size_t)(rowBase + rr) * PD + (KT) * BK + cc * 8; \
      __builtin_amdgcn_global_load_lds((gas_ptr)ga, (las_ptr)((DSTA) + issue * 1024), 16, 0, 0); \
      if (!diagBlk) {                                                         \
        const __hip_bfloat16* gb = zn + (size_t)(colBase + rr) * PD + (KT) * BK + cc * 8; \
        __builtin_amdgcn_global_load_lds((gas_ptr)gb, (las_ptr)((DSTB) + issue * 1024), 16, 0, 0); \
      }                                                                       \
    }                                                                         \
  } while (0)

  STAGE(lds, lds + 16384, 0);
  __syncthreads();

  for (int kt = 0; kt < PD / BK; ++kt) {         // 4 kt steps
    char* As = lds + (kt & 1) * 32768;
    char* Bs = As + 16384;
    if (kt < PD / BK - 1) {                      // prefetch next slab (dbuf)
      char* An = lds + ((kt + 1) & 1) * 32768;
      STAGE(An, An + 16384, kt + 1);
    }
    const char* BsEff = diagBlk ? As : Bs;

    #pragma unroll
    for (int ki = 0; ki < 2; ++ki) {             // two k=32 MFMA steps per BK=64
      bf16x8 a[4], b[4];
      #pragma unroll
      for (int mi = 0; mi < 4; ++mi) {
        int r = waveRow + mi * 16 + c16;         // A row: m = lane&15
        int ch = quad + ki * 4;                  // k-chunk: k = ki*32 + quad*8 + j
        a[mi] = *(const bf16x8*)(As + r * 128 + ((ch ^ (r & 7)) * 16));
      }
      #pragma unroll
      for (int ni = 0; ni < 4; ++ni) {
        int r = waveCol + ni * 16 + c16;         // B "row" of zn = sim column n
        int ch = quad + ki * 4;
        b[ni] = *(const bf16x8*)(BsEff + r * 128 + ((ch ^ (r & 7)) * 16));
      }
      #pragma unroll
      for (int mi = 0; mi < 4; ++mi)
        #pragma unroll
        for (int ni = 0; ni < 4; ++ni)
          acc[mi][ni] = __builtin_amdgcn_mfma_f32_16x16x32_bf16(a[mi], b[ni], acc[mi][ni], 0, 0, 0);
    }
    if (kt < PD / BK - 1) __syncthreads();       // one barrier per step
  }
#undef STAGE

  // Epilogue. C/D layout: col=lane&15, row=quad*4+reg  [measured m89/m91]
  float colsum[4] = {0.f, 0.f, 0.f, 0.f};   // per-ni column partials (off-diag)
  #pragma unroll
  for (int mi = 0; mi < 4; ++mi) {
    int rbase = rowBase + waveRow + mi * 16 + quad * 4;
    float rs[4] = {0.f, 0.f, 0.f, 0.f};
    #pragma unroll
    for (int ni = 0; ni < 4; ++ni) {
      int gcol = colBase + waveCol + ni * 16 + c16;
      #pragma unroll
      for (int t = 0; t < 4; ++t) {
        int grow = rbase + t;
        float sim = acc[mi][ni][t];
        float e = __expf(2.0f * sim);               // exp(sim / T), T=0.5
        if (diagBlk && gcol == grow) e = 0.0f;      // mask diagonal
        rs[t] += e;
        colsum[ni] += e;
        if (posBlk && gcol == grow + PN) {          // positive pair (and mirror)
          atomicAdd(&pos[grow], sim);               // atomic -> coherent point
          atomicAdd(&pos[grow + PN], sim);
        }
      }
    }
    #pragma unroll
    for (int t = 0; t < 4; ++t) {
      #pragma unroll
      for (int off = 1; off <= 8; off <<= 1) rs[t] += __shfl_xor(rs[t], off, 64);
    }
    if (c16 == 0) {
      #pragma unroll
      for (int t = 0; t < 4; ++t) atomicAdd(&rowsum[rbase + t], rs[t]);
    }
  }
  if (!diagBlk) {   // column contributions = mirrored rows (symmetry)
    #pragma unroll
    for (int ni = 0; ni < 4; ++ni) {
      float cs = colsum[ni];
      cs += __shfl_xor(cs, 16, 64);
      cs += __shfl_xor(cs, 32, 64);
      if (quad == 0) atomicAdd(&rowsum[colBase + waveCol + ni * 16 + c16], cs);
    }
  }

  // ---- Fused finalize: last-finished block reduces rowsum/pos -> out ----
  int* flag = (int*)lds;                     // LDS tiles dead past this point
  __syncthreads();                           // drains each wave's atomics (vmcnt 0)
  if (tid == 0) {
    __threadfence();
    unsigned t = atomicAdd(ticket, 1u);
    *flag = (t == NTRI - 1) ? 1 : 0;
  }
  __syncthreads();
  if (*flag == 0) return;

  float wl = 0.f, wsum = 0.f;
  for (int i = tid; i < PN2; i += 256) {
    float rsv = atomicAdd(&rowsum[i], 0.0f);   // coherent read (cross-XCD safe)
    float pv  = atomicAdd(&pos[i], 0.0f);
    float wi  = w[i & (PN - 1)];
    wl += wi * (logf(rsv) - 2.0f * pv);        // loss_i = log(denom) - 2*pos
    wsum += wi;
  }
  #pragma unroll
  for (int off = 32; off >= 1; off >>= 1) {
    wl += __shfl_xor(wl, off, 64);
    wsum += __shfl_xor(wsum, off, 64);
  }
  float* pl = (float*)(lds + 64);
  float* pw = (float*)(lds + 128);
  if ((tid & 63) == 0) { pl[tid >> 6] = wl; pw[tid >> 6] = wsum; }
  __syncthreads();
  if (tid == 0)
    out[0] = (pl[0] + pl[1] + pl[2] + pl[3]) / (pw[0] + pw[1] + pw[2] + pw[3]);
}

// ---------------------------------------------------------------------------
extern "C" void kernel_launch(void* const* d_in, const int* in_sizes, int n_in,
                              void* d_out, int out_size, void* d_ws, size_t ws_size,
                              hipStream_t stream) {
  const float* zi = (const float*)d_in[0];
  const float* zj = (const float*)d_in[1];
  const float* w  = (const float*)d_in[2];
  float* out = (float*)d_out;

  // Workspace: zn bf16 [8192*256] = 4 MiB, rowsum f32[8192], pos f32[8192], ticket u32
  __hip_bfloat16* zn = (__hip_bfloat16*)d_ws;
  float* rowsum = (float*)((char*)d_ws + (size_t)PN2 * PD * 2);
  float* pos = rowsum + PN2;
  unsigned* ticket = (unsigned*)(pos + PN2);

  normalize_kernel<<<PN2 / 4, 256, 0, stream>>>(zi, zj, zn, rowsum, pos, ticket);
  simsum_kernel<<<NTRI, 256, 0, stream>>>(zn, rowsum, pos, w, out, ticket);
}

// Round 3
// 109.133 us; speedup vs baseline: 1.3879x; 1.2398x over previous
//
#include <hip/hip_runtime.h>
#include <hip/hip_bf16.h>

// Problem constants (fixed by reference): N=4096, D=256, T=0.5, EPS=1e-8
#define PN   4096
#define PN2  8192
#define PD   256
#define TILE 128
#define BK   64
#define NBLK (PN2 / TILE)              // 64 tile-blocks per dim
#define NTRI (NBLK * (NBLK + 1) / 2)   // 2080 upper-tri blocks (2080 % 8 == 0)

typedef __attribute__((ext_vector_type(8))) short bf16x8;   // 8 bf16 = 4 VGPRs
typedef __attribute__((ext_vector_type(4))) float f32x4;

typedef const __attribute__((address_space(1))) void* gas_ptr;
typedef __attribute__((address_space(3))) void* las_ptr;

// ---------------------------------------------------------------------------
// Kernel 1: row-normalize z = [z_i; z_j] (fp32), write bf16 zn; zero the
// tiny finalize scratch. Wave-per-row: float4 loads, shuffle-reduce, 8B store.
// ---------------------------------------------------------------------------
__global__ __launch_bounds__(256) void normalize_kernel(
    const float* __restrict__ zi, const float* __restrict__ zj,
    __hip_bfloat16* __restrict__ zn, float* __restrict__ wlws,
    unsigned* __restrict__ ticket) {
  const int wave = threadIdx.x >> 6;
  const int lane = threadIdx.x & 63;
  const int r = blockIdx.x * 4 + wave;           // 0..8191
  const float* src = (r < PN) ? (zi + (size_t)r * PD) : (zj + (size_t)(r - PN) * PD);
  float4 x = *(const float4*)(src + lane * 4);   // 16B/lane, coalesced
  float s = x.x * x.x + x.y * x.y + x.z * x.z + x.w * x.w;
  #pragma unroll
  for (int off = 32; off >= 1; off >>= 1) s += __shfl_xor(s, off, 64);
  float inv = 1.0f / fmaxf(sqrtf(s), 1e-8f);
  union { ushort4 u; __hip_bfloat16 h[4]; } o;
  o.h[0] = __float2bfloat16(x.x * inv);
  o.h[1] = __float2bfloat16(x.y * inv);
  o.h[2] = __float2bfloat16(x.z * inv);
  o.h[3] = __float2bfloat16(x.w * inv);
  *(ushort4*)((unsigned short*)zn + (size_t)r * PD + lane * 4) = o.u;  // 8B/lane
  if (r == 0) {                                   // ws is poisoned 0xAA pre-launch
    if (lane == 0) { wlws[0] = 0.0f; wlws[1] = 0.0f; }
    if (lane == 1) *ticket = 0u;
  }
}

// ---------------------------------------------------------------------------
// Kernel 2: sim = zn @ zn^T, UPPER-TRIANGULAR blocks only (symmetry).
// EXACT round-0 K-loop (proven 43.8us). Epilogue rewritten: NO global atomics.
// Per-block partials accumulate in LDS (ds-atomics), then ONE plain store per
// row into rowpart[64][8192]:
//   row-partials of block (bi,bj) -> rowpart[bj][bi*128 .. +128)
//   col-partials of block (bi,bj) -> rowpart[bi][bj*128 .. +128)   (bi<bj)
// Writers are provably unique and every entry is written exactly once
// (diag block (b,b) writes rowpart[b][b-band], no col-partials).
// XCD-aware bijective swizzle (2080 % 8 == 0) clusters same-bj blocks per XCD.
// ---------------------------------------------------------------------------
__global__ __launch_bounds__(256) void simsum_kernel(
    const __hip_bfloat16* __restrict__ zn,
    float* __restrict__ rowpart, float* __restrict__ pos) {
  __shared__ char lds[2 * TILE * BK * 2];   // 32 KiB: As then Bs
  __shared__ float rowacc[TILE];
  __shared__ float colacc[TILE];
  char* As = lds;
  char* Bs = lds + TILE * BK * 2;

  const int tid  = threadIdx.x;
  if (tid < TILE) { rowacc[tid] = 0.0f; colacc[tid] = 0.0f; }

  // XCD swizzle: 8 XCDs, 260 blocks each (bijective since 2080 % 8 == 0)
  const int idx = (int)((blockIdx.x & 7) * (NTRI / 8) + (blockIdx.x >> 3));
  // Decode upper-tri (bi<=bj): idx = T(bj) + bi, T(bj)=bj(bj+1)/2
  int bj = (int)((sqrtf(8.0f * (float)idx + 1.0f) - 1.0f) * 0.5f);
  while ((bj + 1) * (bj + 2) / 2 <= idx) ++bj;
  while (bj * (bj + 1) / 2 > idx) --bj;
  const int bi = idx - bj * (bj + 1) / 2;
  const bool diagBlk = (bi == bj);
  const bool posBlk  = (bj == bi + PN / TILE);   // cols == rows + 4096

  const int wave = tid >> 6;
  const int lane = tid & 63;
  const int quad = lane >> 4;
  const int c16  = lane & 15;
  const int rowBase = bi * TILE;
  const int colBase = bj * TILE;
  const int waveRow = (wave >> 1) * 64;
  const int waveCol = (wave & 1) * 64;

  f32x4 acc[4][4];
  #pragma unroll
  for (int i = 0; i < 4; ++i)
    #pragma unroll
    for (int j = 0; j < 4; ++j)
      acc[i][j] = (f32x4){0.f, 0.f, 0.f, 0.f};

  const int subrow = lane >> 3;  // 0..7 (row within an 8-row issue)
  const int slot   = lane & 7;   // 0..7 (16B chunk slot within a 128B LDS row)
  const char* BsEff = diagBlk ? As : Bs;

  for (int kt = 0; kt < PD / BK; ++kt) {
    if (kt) __syncthreads();     // protect LDS before overwrite
    #pragma unroll
    for (int p = 0; p < 4; ++p) {
      int issue = wave * 4 + p;            // 0..15, wave-uniform
      int r = issue * 8 + subrow;          // tile row 0..127
      int c = slot ^ (r & 7);              // swizzled k-chunk for this lane
      const __hip_bfloat16* ga = zn + (size_t)(rowBase + r) * PD + kt * BK + c * 8;
      __builtin_amdgcn_global_load_lds((gas_ptr)ga, (las_ptr)(As + issue * 1024), 16, 0, 0);
      if (!diagBlk) {
        const __hip_bfloat16* gb = zn + (size_t)(colBase + r) * PD + kt * BK + c * 8;
        __builtin_amdgcn_global_load_lds((gas_ptr)gb, (las_ptr)(Bs + issue * 1024), 16, 0, 0);
      }
    }
    __syncthreads();             // s_waitcnt vmcnt(0) before s_barrier

    #pragma unroll
    for (int ki = 0; ki < 2; ++ki) {       // two k=32 MFMA steps per BK=64
      bf16x8 a[4], b[4];
      #pragma unroll
      for (int mi = 0; mi < 4; ++mi) {
        int r = waveRow + mi * 16 + c16;   // A row: m = lane&15
        int ch = quad + ki * 4;            // k-chunk: k = ki*32 + quad*8 + j
        a[mi] = *(const bf16x8*)(As + r * 128 + ((ch ^ (r & 7)) * 16));
      }
      #pragma unroll
      for (int ni = 0; ni < 4; ++ni) {
        int r = waveCol + ni * 16 + c16;   // B "row" of zn = sim column n
        int ch = quad + ki * 4;
        b[ni] = *(const bf16x8*)(BsEff + r * 128 + ((ch ^ (r & 7)) * 16));
      }
      #pragma unroll
      for (int mi = 0; mi < 4; ++mi)
        #pragma unroll
        for (int ni = 0; ni < 4; ++ni)
          acc[mi][ni] = __builtin_amdgcn_mfma_f32_16x16x32_bf16(a[mi], b[ni], acc[mi][ni], 0, 0, 0);
    }
  }

  // Epilogue. C/D layout: col=lane&15, row=quad*4+reg  [measured m89/m91]
  float colsum[4] = {0.f, 0.f, 0.f, 0.f};   // per-ni column partials (off-diag)
  #pragma unroll
  for (int mi = 0; mi < 4; ++mi) {
    int lrow = waveRow + mi * 16 + quad * 4;      // local row 0..127
    float rs[4] = {0.f, 0.f, 0.f, 0.f};
    #pragma unroll
    for (int ni = 0; ni < 4; ++ni) {
      int gcol = colBase + waveCol + ni * 16 + c16;
      #pragma unroll
      for (int t = 0; t < 4; ++t) {
        int grow = rowBase + lrow + t;
        float sim = acc[mi][ni][t];
        float e = __expf(2.0f * sim);               // exp(sim / T), T=0.5
        if (diagBlk && gcol == grow) e = 0.0f;      // mask diagonal
        rs[t] += e;
        colsum[ni] += e;
        if (posBlk && gcol == grow + PN) {          // positive pair (and mirror)
          pos[grow] = sim;                           // unique writer per row
          pos[grow + PN] = sim;
        }
      }
    }
    #pragma unroll
    for (int t = 0; t < 4; ++t) {
      #pragma unroll
      for (int off = 1; off <= 8; off <<= 1) rs[t] += __shfl_xor(rs[t], off, 64);
    }
    if (c16 == 0) {                                  // LDS atomics: cheap, per-CU
      #pragma unroll
      for (int t = 0; t < 4; ++t) atomicAdd(&rowacc[lrow + t], rs[t]);
    }
  }
  if (!diagBlk) {   // column contributions = mirrored rows (symmetry)
    #pragma unroll
    for (int ni = 0; ni < 4; ++ni) {
      float cs = colsum[ni];
      cs += __shfl_xor(cs, 16, 64);
      cs += __shfl_xor(cs, 32, 64);
      if (quad == 0) atomicAdd(&colacc[waveCol + ni * 16 + c16], cs);
    }
  }

  __syncthreads();                // all LDS accumulation done
  if (tid < TILE) {               // plain stores, unique writers (see header)
    rowpart[(size_t)bj * PN2 + rowBase + tid] = rowacc[tid];
    if (!diagBlk)
      rowpart[(size_t)bi * PN2 + colBase + tid] = colacc[tid];
  }
}

// ---------------------------------------------------------------------------
// Kernel 3: rowsum[r] = sum_x rowpart[x][r]; loss_r = log(rowsum)-2*pos;
// out = sum(w*loss)/sum(w). 32 blocks x 256 threads, 1 row/thread.
// ---------------------------------------------------------------------------
__global__ __launch_bounds__(256) void finalize_kernel(
    const float* __restrict__ rowpart, const float* __restrict__ pos,
    const float* __restrict__ w, float* __restrict__ wlws,
    unsigned* __restrict__ ticket, float* __restrict__ out) {
  const int tid = threadIdx.x;
  const int r = blockIdx.x * 256 + tid;     // 32*256 = 8192
  float s = 0.0f;
  #pragma unroll 8
  for (int x = 0; x < NBLK; ++x) s += rowpart[(size_t)x * PN2 + r];
  float li = logf(s) - 2.0f * pos[r];
  float wi = w[r & (PN - 1)];
  float wl = wi * li, ws = wi;
  #pragma unroll
  for (int off = 32; off >= 1; off >>= 1) {
    wl += __shfl_xor(wl, off, 64);
    ws += __shfl_xor(ws, off, 64);
  }
  __shared__ float pl[4], pw[4];
  const int lane = tid & 63, wv = tid >> 6;
  if (lane == 0) { pl[wv] = wl; pw[wv] = ws; }
  __syncthreads();
  if (tid == 0) {
    atomicAdd(&wlws[0], pl[0] + pl[1] + pl[2] + pl[3]);
    atomicAdd(&wlws[1], pw[0] + pw[1] + pw[2] + pw[3]);
    __threadfence();
    if (atomicAdd(ticket, 1u) == 31) {      // last of 32 blocks
      float a = atomicAdd(&wlws[0], 0.0f);  // coherent re-read
      float b = atomicAdd(&wlws[1], 0.0f);
      out[0] = a / b;
    }
  }
}

// ---------------------------------------------------------------------------
extern "C" void kernel_launch(void* const* d_in, const int* in_sizes, int n_in,
                              void* d_out, int out_size, void* d_ws, size_t ws_size,
                              hipStream_t stream) {
  const float* zi = (const float*)d_in[0];
  const float* zj = (const float*)d_in[1];
  const float* w  = (const float*)d_in[2];
  float* out = (float*)d_out;

  // Workspace: zn bf16[8192*256]=4MiB | rowpart f32[64][8192]=2MiB |
  //            pos f32[8192]=32KiB | wlws f32[2] | ticket u32
  __hip_bfloat16* zn = (__hip_bfloat16*)d_ws;
  float* rowpart = (float*)((char*)d_ws + (size_t)PN2 * PD * 2);
  float* pos     = rowpart + (size_t)NBLK * PN2;
  float* wlws    = pos + PN2;
  unsigned* ticket = (unsigned*)(wlws + 2);

  normalize_kernel<<<PN2 / 4, 256, 0, stream>>>(zi, zj, zn, wlws, ticket);
  simsum_kernel<<<NTRI, 256, 0, stream>>>(zn, rowpart, pos);
  finalize_kernel<<<32, 256, 0, stream>>>(rowpart, pos, w, wlws, ticket, out);
}